// Round 7
// baseline (333.352 us; speedup 1.0000x reference)
//
#include <hip/hip_runtime.h>
#include <hip/hip_bf16.h>

// Fused additive-attention (Bahdanau-style) on MI355X.
//   att1 = enc @ W_enc + b_enc            [B,L,A]  (bf16 MFMA, fp32 accum)
//   att2 = dh @ W_dec + b_dec             [B,A]
//   s    = tanh(att1+att2) . W_full       [B,L]    (b_full dropped: softmax-invariant)
//   alpha= softmax_L(s); awe = sum_l alpha * att1  [B,A]
// Flash-style two-level softmax: att1 never hits HBM.
//
// R7 vs R6 (246.8us): wave layout 16x(64r x 32c) -> 8x(64r x 64c).
//   A-LDS read amplification 16 -> 8 (halves the modeled binding resource,
//   78 -> 39us/CU); B L2 traffic unchanged (B-dup stays 1). acc[4][4]=64
//   VGPR + B double-set 64 VGPR -> ~180 regs, 2 waves/SIMD, 512-thr block
//   (HK-style ILP regime). Pipeline structure identical to R6.

#define Bn 64
#define Ln 1024
#define En 2048
#define An 512
#define TM 64          // l-rows per workgroup
#define NTILES (Ln/TM) // 16
#define AWE_OFF 0
#define ALPHA_OFF (Bn*An) // 32768
#define TILEB 8192     // bytes per A k-tile LDS buffer

using short8 = __attribute__((ext_vector_type(8))) short;
using f32x4  = __attribute__((ext_vector_type(4))) float;

__device__ inline short f2bf(float x){
    unsigned u = __builtin_bit_cast(unsigned, x);
    unsigned r = (u + 0x7fffu + ((u >> 16) & 1u)) >> 16;
    return (short)r;
}
__device__ inline float tanh_fast(float x){
    return 2.0f * __frcp_rn(1.0f + __expf(-2.0f * x)) - 1.0f;
}

// ---------- kernel 0: W_enc fragment-pack  +  att2 GEMV (merged) ----------
__global__ __launch_bounds__(256) void k_prep(const float* __restrict__ W,
                                              unsigned short* __restrict__ Wp,
                                              const float* __restrict__ dh,
                                              const float* __restrict__ Wd,
                                              const float* __restrict__ bd,
                                              float* __restrict__ att2){
    __shared__ float dl[512];
    int blk = blockIdx.x, tid = threadIdx.x;
    if (blk < 512){
        int t = blk * 256 + tid;
        int f = t >> 6, lane = t & 63;
        int kb = f >> 5, nc = f & 31;
        int k0 = kb * 32 + (lane >> 4) * 8;
        int col = nc * 16 + (lane & 15);
        short8 v;
#pragma unroll
        for (int j = 0; j < 8; ++j)
            v[j] = f2bf(W[(size_t)(k0 + j) * An + col]);
        *(short8*)(Wp + (size_t)f * 512 + lane * 8) = v;
    } else {
        int b = blk - 512;
        dl[tid]       = dh[b * 512 + tid];
        dl[tid + 256] = dh[b * 512 + tid + 256];
        __syncthreads();
        for (int a = tid; a < An; a += 256){
            float s = bd[a];
            for (int k = 0; k < 512; ++k)
                s = fmaf(dl[k], Wd[(size_t)k * An + a], s);
            att2[b * An + a] = s;
        }
    }
}

// ---------- kernel 1: fused GEMM + score + tile-softmax + partial awe ----------
// 512 threads = 8 waves, wave w owns rows 0..63 x cols [w*64, w*64+64).
// acc[mi][ni]: mi = row block (mi*16), ni = col block (w*64 + ni*16).

#define MFMA(a, b, c) __builtin_amdgcn_mfma_f32_16x16x32_bf16((a), (b), (c), 0, 0, 0)

// Issue phase-P B loads (8 frags: s in {0,1} x ni in {0..3}) into set S.
#define BLOAD(S, P)                                                           \
    { int pc = (P) > 31 ? 31 : (P);                                           \
      const unsigned short* bp = Bbase + (size_t)pc * 32768;                  \
      S##00 = *(const short8*)(bp);                                           \
      S##01 = *(const short8*)(bp + 512);                                     \
      S##02 = *(const short8*)(bp + 1024);                                    \
      S##03 = *(const short8*)(bp + 1536);                                    \
      S##10 = *(const short8*)(bp + 16384);                                   \
      S##11 = *(const short8*)(bp + 16384 + 512);                             \
      S##12 = *(const short8*)(bp + 16384 + 1024);                            \
      S##13 = *(const short8*)(bp + 16384 + 1536); }

#define STAGE(Q, R0, R1)                                                      \
    { short8 sv;                                                              \
      sv[0] = f2bf(R0.x); sv[1] = f2bf(R0.y);                                 \
      sv[2] = f2bf(R0.z); sv[3] = f2bf(R0.w);                                 \
      sv[4] = f2bf(R1.x); sv[5] = f2bf(R1.y);                                 \
      sv[6] = f2bf(R1.z); sv[7] = f2bf(R1.w);                                 \
      *(short8*)(swp + (Q) * TILEB) = sv; }

// 32 MFMAs for buffer Q using landed register set S.
#define MFMAS(Q, S)                                                           \
    _Pragma("unroll")                                                         \
    for (int mi = 0; mi < 4; ++mi){                                           \
        short8 af0 = *(const short8*)(as0 + (Q) * TILEB + mi * 2048);         \
        short8 af1 = *(const short8*)(as1 + (Q) * TILEB + mi * 2048);         \
        acc[mi][0] = MFMA(af0, S##00, acc[mi][0]);                            \
        acc[mi][1] = MFMA(af0, S##01, acc[mi][1]);                            \
        acc[mi][2] = MFMA(af0, S##02, acc[mi][2]);                            \
        acc[mi][3] = MFMA(af0, S##03, acc[mi][3]);                            \
        acc[mi][0] = MFMA(af1, S##10, acc[mi][0]);                            \
        acc[mi][1] = MFMA(af1, S##11, acc[mi][1]);                            \
        acc[mi][2] = MFMA(af1, S##12, acc[mi][2]);                            \
        acc[mi][3] = MFMA(af1, S##13, acc[mi][3]);                            \
    }

__global__ __launch_bounds__(512)
void k_main(const float* __restrict__ enc, const unsigned short* __restrict__ Wp,
            const float* __restrict__ benc, const float* __restrict__ att2,
            const float* __restrict__ wfull, float* __restrict__ out,
            float* __restrict__ pawe_ws, float* __restrict__ ms_ws){
    const int wg   = blockIdx.x;            // 0..1023
    const int b    = wg >> 4;
    const int tile = wg & 15;
    const int l0   = tile * TM;
    const int tid  = threadIdx.x;
    const int lane = tid & 63, w = tid >> 6;   // w = 0..7 (col-group)

    __shared__ alignas(16) unsigned short Alds[4][TM * 64];  // 4 x 8 KB, XOR-swizzled bf16
    __shared__ float red[8][TM];               // per-wave row score partials
    __shared__ float plds[TM];                 // tile-local exp(s - m)
    char* const alds = (char*)Alds;

    f32x4 acc[4][4];
#pragma unroll
    for (int mi = 0; mi < 4; ++mi)
#pragma unroll
        for (int ni = 0; ni < 4; ++ni)
            acc[mi][ni] = (f32x4){0.f, 0.f, 0.f, 0.f};

    // staging: thread loads 8 fp32 (2x16B) of row (tid>>3), k-chunk (tid&7)*8
    const int srow  = tid >> 3;
    const int sbyte = srow * 128 + (((tid & 7) * 16) ^ ((srow & 7) << 4));
    char* const swp = alds + sbyte;
    const float* apt = enc + ((size_t)(b * Ln + l0 + srow)) * En + (tid & 7) * 8;

    // B fragments: f = (p*2+s)*32 + w*4 + ni ; addr = Wp + f*512 + lane*8
    const unsigned short* Bbase = Wp + (size_t)(w * 4) * 512 + lane * 8;

    // A fragments: row = mi*16 + (lane&15); k-byte = (s*64 + akb) ^ sw (full XOR)
    const int arow = lane & 15;
    const int akb  = (lane >> 4) * 16;
    const int sw   = (arow & 7) << 4;
    const char* const as0 = alds + arow * 128 + (akb ^ sw);
    const char* const as1 = alds + arow * 128 + ((64 + akb) ^ sw);

    // B register sets (double-buffered across phases)
    short8 fa00, fa01, fa02, fa03, fa10, fa11, fa12, fa13;   // even phases
    short8 fb00, fb01, fb02, fb03, fb10, fb11, fb12, fb13;   // odd phases

    // prologue: tiles 0,1 staged; ring (ra*,rb*) holds tiles 2,3; B for phase 0
    float4 ra0 = *(const float4*)(apt);
    float4 ra1 = *(const float4*)(apt + 4);
    float4 rb0 = *(const float4*)(apt + 64);
    float4 rb1 = *(const float4*)(apt + 68);
    STAGE(0, ra0, ra1)
    STAGE(1, rb0, rb1)
    ra0 = *(const float4*)(apt + 2 * 64);
    ra1 = *(const float4*)(apt + 2 * 64 + 4);
    rb0 = *(const float4*)(apt + 3 * 64);
    rb1 = *(const float4*)(apt + 3 * 64 + 4);
    BLOAD(fa, 0)

    for (int p = 0; p < 32; p += 4){
        __syncthreads();
        {   // phase p: issue B(p+1); stage p+2,p+3 -> Q2,Q3; reload ring; MFMA Q0 (fa)
            BLOAD(fb, p + 1)
            STAGE(2, ra0, ra1)
            STAGE(3, rb0, rb1)
            int t0 = p + 4 > 31 ? 31 : p + 4;   // clamped tail loads (unread)
            int t1 = p + 5 > 31 ? 31 : p + 5;
            ra0 = *(const float4*)(apt + t0 * 64);
            ra1 = *(const float4*)(apt + t0 * 64 + 4);
            rb0 = *(const float4*)(apt + t1 * 64);
            rb1 = *(const float4*)(apt + t1 * 64 + 4);
            MFMAS(0, fa)
        }
        {   // phase p+1: issue B(p+2); MFMA Q1 (fb)
            BLOAD(fa, p + 2)
            MFMAS(1, fb)
        }
        __syncthreads();
        {   // phase p+2: issue B(p+3); stage p+4,p+5 -> Q0,Q1; reload ring; MFMA Q2 (fa)
            BLOAD(fb, p + 3)
            STAGE(0, ra0, ra1)
            STAGE(1, rb0, rb1)
            int t0 = p + 6 > 31 ? 31 : p + 6;
            int t1 = p + 7 > 31 ? 31 : p + 7;
            ra0 = *(const float4*)(apt + t0 * 64);
            ra1 = *(const float4*)(apt + t0 * 64 + 4);
            rb0 = *(const float4*)(apt + t1 * 64);
            rb1 = *(const float4*)(apt + t1 * 64 + 4);
            MFMAS(2, fa)
        }
        {   // phase p+3: issue B(p+4); MFMA Q3 (fb)
            BLOAD(fa, p + 4)
            MFMAS(3, fb)
        }
    }

    // ---- epilogue ----
    float be[4], a2[4], wfv[4];
    const int cbase = w * 64 + (lane & 15);
#pragma unroll
    for (int ni = 0; ni < 4; ++ni){
        int c = cbase + ni * 16;
        be[ni]  = benc[c];
        a2[ni]  = att2[b * An + c];
        wfv[ni] = wfull[c];
    }

    float tsum[4][4];
#pragma unroll
    for (int mi = 0; mi < 4; ++mi)
#pragma unroll
        for (int j = 0; j < 4; ++j)
            tsum[mi][j] = 0.f;
#pragma unroll
    for (int mi = 0; mi < 4; ++mi)
#pragma unroll
        for (int ni = 0; ni < 4; ++ni)
#pragma unroll
            for (int j = 0; j < 4; ++j){
                float vv = acc[mi][ni][j] + be[ni];
                acc[mi][ni][j] = vv;
                tsum[mi][j] += tanh_fast(vv + a2[ni]) * wfv[ni];
            }

#pragma unroll
    for (int mi = 0; mi < 4; ++mi)
#pragma unroll
        for (int j = 0; j < 4; ++j){
            float t = tsum[mi][j];
            t += __shfl_xor(t, 1); t += __shfl_xor(t, 2);
            t += __shfl_xor(t, 4); t += __shfl_xor(t, 8);
            if ((lane & 15) == 0)
                red[w][mi * 16 + (lane >> 4) * 4 + j] = t;
        }
    __syncthreads();

    if (tid < 64){   // wave 0: combine 8 wave-partials, tile softmax stats
        float s = 0.f;
#pragma unroll
        for (int k = 0; k < 8; ++k)
            s += red[k][tid];
        out[ALPHA_OFF + b * Ln + l0 + tid] = s;   // raw score; finalized in k_final
        float m = s;
        m = fmaxf(m, __shfl_xor(m, 1));  m = fmaxf(m, __shfl_xor(m, 2));
        m = fmaxf(m, __shfl_xor(m, 4));  m = fmaxf(m, __shfl_xor(m, 8));
        m = fmaxf(m, __shfl_xor(m, 16)); m = fmaxf(m, __shfl_xor(m, 32));
        float pv = __expf(s - m);
        float sm = pv;
        sm += __shfl_xor(sm, 1);  sm += __shfl_xor(sm, 2);
        sm += __shfl_xor(sm, 4);  sm += __shfl_xor(sm, 8);
        sm += __shfl_xor(sm, 16); sm += __shfl_xor(sm, 32);
        plds[tid] = pv;
        if (tid == 0){ ms_ws[wg * 2] = m; ms_ws[wg * 2 + 1] = sm; }
    }
    __syncthreads();

    // partial awe for this wave's 64 cols (rows complete within the wave)
    float pp[4];
#pragma unroll
    for (int ni = 0; ni < 4; ++ni) pp[ni] = 0.f;
#pragma unroll
    for (int mi = 0; mi < 4; ++mi)
#pragma unroll
        for (int j = 0; j < 4; ++j){
            float pr = plds[mi * 16 + (lane >> 4) * 4 + j];
#pragma unroll
            for (int ni = 0; ni < 4; ++ni)
                pp[ni] += pr * acc[mi][ni][j];
        }
#pragma unroll
    for (int ni = 0; ni < 4; ++ni){
        pp[ni] += __shfl_xor(pp[ni], 16);
        pp[ni] += __shfl_xor(pp[ni], 32);
    }
    if (lane < 16){
#pragma unroll
        for (int ni = 0; ni < 4; ++ni)
            pawe_ws[(size_t)wg * An + w * 64 + ni * 16 + lane] = pp[ni];
    }
}

// ---------- kernel 2: combine tiles, finalize awe + alpha ----------
__global__ __launch_bounds__(256) void k_final(const float* __restrict__ pawe,
                                               const float* __restrict__ ms,
                                               float* __restrict__ out){
    int b = blockIdx.x, tid = threadIdx.x;
    __shared__ float scale[NTILES];
    __shared__ float sh[2];   // inv_total, global max
    if (tid < 64){
        int lane = tid;
        float m = -1e30f, su = 0.f;
        if (lane < NTILES){ m = ms[(b * NTILES + lane) * 2]; su = ms[(b * NTILES + lane) * 2 + 1]; }
        float mm = m;
        mm = fmaxf(mm, __shfl_xor(mm, 1)); mm = fmaxf(mm, __shfl_xor(mm, 2));
        mm = fmaxf(mm, __shfl_xor(mm, 4)); mm = fmaxf(mm, __shfl_xor(mm, 8));
        float sc = (lane < NTILES) ? su * __expf(m - mm) : 0.f;
        float tot = sc;
        tot += __shfl_xor(tot, 1); tot += __shfl_xor(tot, 2);
        tot += __shfl_xor(tot, 4); tot += __shfl_xor(tot, 8);
        if (lane < NTILES) scale[lane] = __expf(m - mm);
        if (lane == 0){ sh[0] = 1.0f / tot; sh[1] = mm; }
    }
    __syncthreads();
    float inv = sh[0], mm = sh[1];
    for (int a = tid; a < An; a += 256){
        float s = 0.f;
#pragma unroll
        for (int t = 0; t < NTILES; ++t)
            s += pawe[((size_t)(b * NTILES + t)) * An + a] * scale[t];
        out[AWE_OFF + b * An + a] = s * inv;
    }
    for (int l = tid; l < Ln; l += 256){
        float s = out[ALPHA_OFF + b * Ln + l];
        out[ALPHA_OFF + b * Ln + l] = __expf(s - mm) * inv;
    }
}

extern "C" void kernel_launch(void* const* d_in, const int* in_sizes, int n_in,
                              void* d_out, int out_size, void* d_ws, size_t ws_size,
                              hipStream_t stream){
    const float* enc   = (const float*)d_in[0];
    const float* dh    = (const float*)d_in[1];
    const float* Wenc  = (const float*)d_in[2];
    const float* benc  = (const float*)d_in[3];
    const float* Wdec  = (const float*)d_in[4];
    const float* bdec  = (const float*)d_in[5];
    const float* wfull = (const float*)d_in[6];
    // d_in[7] = b_full: softmax-invariant, unused.
    float* out = (float*)d_out;

    char* ws = (char*)d_ws;
    unsigned short* Wp = (unsigned short*)ws;                       // 2 MB packed W
    float* att2 = (float*)(ws + (2u << 20));                        // 128 KB
    float* pawe = (float*)(ws + (2u << 20) + (128u << 10));         // 2 MB
    float* msb  = (float*)(ws + (4u << 20) + (128u << 10));         // 8 KB

    k_prep<<<576, 256, 0, stream>>>(Wenc, Wp, dh, Wdec, bdec, att2);
    k_main<<<Bn * NTILES, 512, 0, stream>>>(enc, Wp, benc, att2, wfull, out, pawe, msb);
    k_final<<<Bn, 256, 0, stream>>>(pawe, msb, out);
}

// Round 8
// 318.424 us; speedup vs baseline: 1.0469x; 1.0469x over previous
//
#include <hip/hip_runtime.h>
#include <hip/hip_bf16.h>

// Fused additive-attention (Bahdanau-style) on MI355X.
//   att1 = enc @ W_enc + b_enc            [B,L,A]  (bf16 MFMA, fp32 accum)
//   att2 = dh @ W_dec + b_dec             [B,A]
//   s    = tanh(att1+att2) . W_full       [B,L]    (b_full dropped: softmax-invariant)
//   alpha= softmax_L(s); awe = sum_l alpha * att1  [B,A]
// Flash-style two-level softmax: att1 never hits HBM.
//
// R8 vs R6 (246.8us) / R7 (333us, regression from 2-waves/SIMD):
//   TM 64 -> 128, grid 1024 -> 512, wave = 128 rows x 32 cols (16 waves,
//   1024 thr). B(Wp) L2/L3 traffic HALVES (2GB -> 1GB) since B-dup stays 1
//   and blocks halve. Pipeline identical to R6 (quad-buffer A-LDS, B-reg
//   double-set prefetch, enc ring 2 tiles ahead, barrier per 2 phases).
//   acc = 64 AGPR, B-sets 32 VGPR -> still TLP-friendly; LDS 74KB ->
//   2 blocks/CU co-resident (cross-block overlap covers barrier drains).

#define Bn 64
#define Ln 1024
#define En 2048
#define An 512
#define TM 128         // l-rows per workgroup
#define NTILES (Ln/TM) // 8
#define AWE_OFF 0
#define ALPHA_OFF (Bn*An) // 32768
#define TILEB 16384    // bytes per A k-tile LDS buffer (128 rows x 128B)

using short8 = __attribute__((ext_vector_type(8))) short;
using f32x4  = __attribute__((ext_vector_type(4))) float;

__device__ inline short f2bf(float x){
    unsigned u = __builtin_bit_cast(unsigned, x);
    unsigned r = (u + 0x7fffu + ((u >> 16) & 1u)) >> 16;
    return (short)r;
}
__device__ inline float tanh_fast(float x){
    return 2.0f * __frcp_rn(1.0f + __expf(-2.0f * x)) - 1.0f;
}

// ---------- kernel 0: W_enc fragment-pack  +  att2 GEMV (merged) ----------
__global__ __launch_bounds__(256) void k_prep(const float* __restrict__ W,
                                              unsigned short* __restrict__ Wp,
                                              const float* __restrict__ dh,
                                              const float* __restrict__ Wd,
                                              const float* __restrict__ bd,
                                              float* __restrict__ att2){
    __shared__ float dl[512];
    int blk = blockIdx.x, tid = threadIdx.x;
    if (blk < 512){
        int t = blk * 256 + tid;
        int f = t >> 6, lane = t & 63;
        int kb = f >> 5, nc = f & 31;
        int k0 = kb * 32 + (lane >> 4) * 8;
        int col = nc * 16 + (lane & 15);
        short8 v;
#pragma unroll
        for (int j = 0; j < 8; ++j)
            v[j] = f2bf(W[(size_t)(k0 + j) * An + col]);
        *(short8*)(Wp + (size_t)f * 512 + lane * 8) = v;
    } else {
        int b = blk - 512;
        dl[tid]       = dh[b * 512 + tid];
        dl[tid + 256] = dh[b * 512 + tid + 256];
        __syncthreads();
        for (int a = tid; a < An; a += 256){
            float s = bd[a];
            for (int k = 0; k < 512; ++k)
                s = fmaf(dl[k], Wd[(size_t)k * An + a], s);
            att2[b * An + a] = s;
        }
    }
}

// ---------- kernel 1: fused GEMM + score + tile-softmax + partial awe ----------
// 1024 threads = 16 waves, wave w owns ALL 128 rows x cols [w*32, w*32+32).
// acc[mi][ni]: mi = row block (mi*16, 0..7), ni = col block (w*32 + ni*16).

#define MFMA(a, b, c) __builtin_amdgcn_mfma_f32_16x16x32_bf16((a), (b), (c), 0, 0, 0)

// Issue phase-P B loads (4 frags: s in {0,1} x ni in {0,1}) into set S.
#define BLOAD(S, P)                                                           \
    { int pc = (P) > 31 ? 31 : (P);                                           \
      const unsigned short* bp = Bbase + (size_t)pc * 32768;                  \
      S##00 = *(const short8*)(bp);                                           \
      S##01 = *(const short8*)(bp + 512);                                     \
      S##10 = *(const short8*)(bp + 16384);                                   \
      S##11 = *(const short8*)(bp + 16384 + 512); }

#define STAGE(Q, R0, R1)                                                      \
    { short8 sv;                                                              \
      sv[0] = f2bf(R0.x); sv[1] = f2bf(R0.y);                                 \
      sv[2] = f2bf(R0.z); sv[3] = f2bf(R0.w);                                 \
      sv[4] = f2bf(R1.x); sv[5] = f2bf(R1.y);                                 \
      sv[6] = f2bf(R1.z); sv[7] = f2bf(R1.w);                                 \
      *(short8*)(swp + (Q) * TILEB) = sv; }

// 32 MFMAs for buffer Q using landed register set S.
#define MFMAS(Q, S)                                                           \
    _Pragma("unroll")                                                         \
    for (int mi = 0; mi < 8; ++mi){                                           \
        short8 af0 = *(const short8*)(as0 + (Q) * TILEB + mi * 2048);         \
        short8 af1 = *(const short8*)(as1 + (Q) * TILEB + mi * 2048);         \
        acc[mi][0] = MFMA(af0, S##00, acc[mi][0]);                            \
        acc[mi][1] = MFMA(af0, S##01, acc[mi][1]);                            \
        acc[mi][0] = MFMA(af1, S##10, acc[mi][0]);                            \
        acc[mi][1] = MFMA(af1, S##11, acc[mi][1]);                            \
    }

__global__ __launch_bounds__(1024)
void k_main(const float* __restrict__ enc, const unsigned short* __restrict__ Wp,
            const float* __restrict__ benc, const float* __restrict__ att2,
            const float* __restrict__ wfull, float* __restrict__ out,
            float* __restrict__ pawe_ws, float* __restrict__ ms_ws){
    const int wg   = blockIdx.x;            // 0..511
    const int b    = wg >> 3;
    const int tile = wg & 7;
    const int l0   = tile * TM;
    const int tid  = threadIdx.x;
    const int lane = tid & 63, w = tid >> 6;   // w = 0..15 (col-group)

    __shared__ alignas(16) unsigned short Alds[4][TM * 64];  // 4 x 16 KB, XOR-swizzled
    __shared__ float red[16][TM];              // per-wave row score partials (8 KB)
    __shared__ float pl[TM];                   // tile-local exp(s - m)
    __shared__ float mred[2], sred[2];
    char* const alds = (char*)Alds;

    f32x4 acc[8][2];
#pragma unroll
    for (int mi = 0; mi < 8; ++mi)
#pragma unroll
        for (int ni = 0; ni < 2; ++ni)
            acc[mi][ni] = (f32x4){0.f, 0.f, 0.f, 0.f};

    // staging: thread loads 8 fp32 (2x16B) of row (tid>>3), k-chunk (tid&7)*8
    const int srow  = tid >> 3;
    const int sbyte = srow * 128 + (((tid & 7) * 16) ^ ((srow & 7) << 4));
    char* const swp = alds + sbyte;
    const float* apt = enc + ((size_t)(b * Ln + l0 + srow)) * En + (tid & 7) * 8;

    // B fragments: f = (p*2+s)*32 + w*2 + ni ; addr = Wp + f*512 + lane*8
    const unsigned short* Bbase = Wp + (size_t)(w * 2) * 512 + lane * 8;

    // A fragments: row = mi*16 + (lane&15); k-byte = (s*64 + akb) ^ sw (full XOR)
    const int arow = lane & 15;
    const int akb  = (lane >> 4) * 16;
    const int sw   = (arow & 7) << 4;
    const char* const as0 = alds + arow * 128 + (akb ^ sw);
    const char* const as1 = alds + arow * 128 + ((64 + akb) ^ sw);

    // B register sets (double-buffered across phases)
    short8 fa00, fa01, fa10, fa11;   // even phases
    short8 fb00, fb01, fb10, fb11;   // odd phases

    // prologue: tiles 0,1 staged; ring (ra*,rb*) holds tiles 2,3; B for phase 0
    float4 ra0 = *(const float4*)(apt);
    float4 ra1 = *(const float4*)(apt + 4);
    float4 rb0 = *(const float4*)(apt + 64);
    float4 rb1 = *(const float4*)(apt + 68);
    STAGE(0, ra0, ra1)
    STAGE(1, rb0, rb1)
    ra0 = *(const float4*)(apt + 2 * 64);
    ra1 = *(const float4*)(apt + 2 * 64 + 4);
    rb0 = *(const float4*)(apt + 3 * 64);
    rb1 = *(const float4*)(apt + 3 * 64 + 4);
    BLOAD(fa, 0)

    for (int p = 0; p < 32; p += 4){
        __syncthreads();
        {   // phase p: issue B(p+1); stage p+2,p+3 -> Q2,Q3; reload ring; MFMA Q0 (fa)
            BLOAD(fb, p + 1)
            STAGE(2, ra0, ra1)
            STAGE(3, rb0, rb1)
            int t0 = p + 4 > 31 ? 31 : p + 4;   // clamped tail loads (unread)
            int t1 = p + 5 > 31 ? 31 : p + 5;
            ra0 = *(const float4*)(apt + t0 * 64);
            ra1 = *(const float4*)(apt + t0 * 64 + 4);
            rb0 = *(const float4*)(apt + t1 * 64);
            rb1 = *(const float4*)(apt + t1 * 64 + 4);
            MFMAS(0, fa)
        }
        {   // phase p+1: issue B(p+2); MFMA Q1 (fb)
            BLOAD(fa, p + 2)
            MFMAS(1, fb)
        }
        __syncthreads();
        {   // phase p+2: issue B(p+3); stage p+4,p+5 -> Q0,Q1; reload ring; MFMA Q2 (fa)
            BLOAD(fb, p + 3)
            STAGE(0, ra0, ra1)
            STAGE(1, rb0, rb1)
            int t0 = p + 6 > 31 ? 31 : p + 6;
            int t1 = p + 7 > 31 ? 31 : p + 7;
            ra0 = *(const float4*)(apt + t0 * 64);
            ra1 = *(const float4*)(apt + t0 * 64 + 4);
            rb0 = *(const float4*)(apt + t1 * 64);
            rb1 = *(const float4*)(apt + t1 * 64 + 4);
            MFMAS(2, fa)
        }
        {   // phase p+3: issue B(p+4); MFMA Q3 (fb)
            BLOAD(fa, p + 4)
            MFMAS(3, fb)
        }
    }

    // ---- epilogue ----
    float be[2], a2[2], wfv[2];
    const int cbase = w * 32 + (lane & 15);
#pragma unroll
    for (int ni = 0; ni < 2; ++ni){
        int c = cbase + ni * 16;
        be[ni]  = benc[c];
        a2[ni]  = att2[b * An + c];
        wfv[ni] = wfull[c];
    }

    float tsum[8][4];
#pragma unroll
    for (int mi = 0; mi < 8; ++mi)
#pragma unroll
        for (int j = 0; j < 4; ++j)
            tsum[mi][j] = 0.f;
#pragma unroll
    for (int mi = 0; mi < 8; ++mi)
#pragma unroll
        for (int ni = 0; ni < 2; ++ni)
#pragma unroll
            for (int j = 0; j < 4; ++j){
                float vv = acc[mi][ni][j] + be[ni];
                acc[mi][ni][j] = vv;
                tsum[mi][j] += tanh_fast(vv + a2[ni]) * wfv[ni];
            }

    // reduce across the 16 lanes of each row-group, stash per-wave partials
#pragma unroll
    for (int mi = 0; mi < 8; ++mi)
#pragma unroll
        for (int j = 0; j < 4; ++j){
            float t = tsum[mi][j];
            t += __shfl_xor(t, 1); t += __shfl_xor(t, 2);
            t += __shfl_xor(t, 4); t += __shfl_xor(t, 8);
            if ((lane & 15) == 0)
                red[w][mi * 16 + (lane >> 4) * 4 + j] = t;
        }
    __syncthreads();

    // tile softmax over TM=128 rows, handled by waves 0 and 1
    float sc_s = 0.f;
    if (tid < TM){
        const int w2 = tid >> 6;
#pragma unroll
        for (int k = 0; k < 16; ++k)
            sc_s += red[k][tid];
        out[ALPHA_OFF + b * Ln + l0 + tid] = sc_s;   // raw score; finalized in k_final
        float m = sc_s;
        m = fmaxf(m, __shfl_xor(m, 1));  m = fmaxf(m, __shfl_xor(m, 2));
        m = fmaxf(m, __shfl_xor(m, 4));  m = fmaxf(m, __shfl_xor(m, 8));
        m = fmaxf(m, __shfl_xor(m, 16)); m = fmaxf(m, __shfl_xor(m, 32));
        if ((tid & 63) == 0) mred[w2] = m;
    }
    __syncthreads();
    if (tid < TM){
        const int w2 = tid >> 6;
        float mm = fmaxf(mred[0], mred[1]);
        float pv = __expf(sc_s - mm);
        pl[tid] = pv;
        float sm = pv;
        sm += __shfl_xor(sm, 1);  sm += __shfl_xor(sm, 2);
        sm += __shfl_xor(sm, 4);  sm += __shfl_xor(sm, 8);
        sm += __shfl_xor(sm, 16); sm += __shfl_xor(sm, 32);
        if ((tid & 63) == 0) sred[w2] = sm;
    }
    __syncthreads();
    if (tid == 0){
        ms_ws[wg * 2]     = fmaxf(mred[0], mred[1]);
        ms_ws[wg * 2 + 1] = sred[0] + sred[1];
    }

    // partial awe for this wave's 32 cols (ALL 128 rows live in this wave)
    float pp0 = 0.f, pp1 = 0.f;
#pragma unroll
    for (int mi = 0; mi < 8; ++mi)
#pragma unroll
        for (int j = 0; j < 4; ++j){
            float pr = pl[mi * 16 + (lane >> 4) * 4 + j];
            pp0 += pr * acc[mi][0][j];
            pp1 += pr * acc[mi][1][j];
        }
    pp0 += __shfl_xor(pp0, 16); pp0 += __shfl_xor(pp0, 32);
    pp1 += __shfl_xor(pp1, 16); pp1 += __shfl_xor(pp1, 32);
    if (lane < 16){
        pawe_ws[(size_t)wg * An + w * 32 + lane]      = pp0;
        pawe_ws[(size_t)wg * An + w * 32 + 16 + lane] = pp1;
    }
}

// ---------- kernel 2: combine tiles, finalize awe + alpha ----------
__global__ __launch_bounds__(256) void k_final(const float* __restrict__ pawe,
                                               const float* __restrict__ ms,
                                               float* __restrict__ out){
    int b = blockIdx.x, tid = threadIdx.x;
    __shared__ float scale[NTILES];
    __shared__ float sh[2];   // inv_total, global max
    if (tid < 64){
        int lane = tid;
        float m = -1e30f, su = 0.f;
        if (lane < NTILES){ m = ms[(b * NTILES + lane) * 2]; su = ms[(b * NTILES + lane) * 2 + 1]; }
        float mm = m;
        mm = fmaxf(mm, __shfl_xor(mm, 1)); mm = fmaxf(mm, __shfl_xor(mm, 2));
        mm = fmaxf(mm, __shfl_xor(mm, 4));
        float sc = (lane < NTILES) ? su * __expf(m - mm) : 0.f;
        float tot = sc;
        tot += __shfl_xor(tot, 1); tot += __shfl_xor(tot, 2);
        tot += __shfl_xor(tot, 4);
        if (lane < NTILES) scale[lane] = __expf(m - mm);
        if (lane == 0){ sh[0] = 1.0f / tot; sh[1] = mm; }
    }
    __syncthreads();
    float inv = sh[0], mm = sh[1];
    for (int a = tid; a < An; a += 256){
        float s = 0.f;
#pragma unroll
        for (int t = 0; t < NTILES; ++t)
            s += pawe[((size_t)(b * NTILES + t)) * An + a] * scale[t];
        out[AWE_OFF + b * An + a] = s * inv;
    }
    for (int l = tid; l < Ln; l += 256){
        float s = out[ALPHA_OFF + b * Ln + l];
        out[ALPHA_OFF + b * Ln + l] = __expf(s - mm) * inv;
    }
}

extern "C" void kernel_launch(void* const* d_in, const int* in_sizes, int n_in,
                              void* d_out, int out_size, void* d_ws, size_t ws_size,
                              hipStream_t stream){
    const float* enc   = (const float*)d_in[0];
    const float* dh    = (const float*)d_in[1];
    const float* Wenc  = (const float*)d_in[2];
    const float* benc  = (const float*)d_in[3];
    const float* Wdec  = (const float*)d_in[4];
    const float* bdec  = (const float*)d_in[5];
    const float* wfull = (const float*)d_in[6];
    // d_in[7] = b_full: softmax-invariant, unused.
    float* out = (float*)d_out;

    char* ws = (char*)d_ws;
    unsigned short* Wp = (unsigned short*)ws;                       // 2 MB packed W
    float* att2 = (float*)(ws + (2u << 20));                        // 128 KB
    float* pawe = (float*)(ws + (2u << 20) + (128u << 10));         // 1 MB (512 wg x 512)
    float* msb  = (float*)(ws + (4u << 20) + (128u << 10));         // 4 KB

    k_prep<<<576, 256, 0, stream>>>(Wenc, Wp, dh, Wdec, bdec, att2);
    k_main<<<Bn * NTILES, 1024, 0, stream>>>(enc, Wp, benc, att2, wfull, out, pawe, msb);
    k_final<<<Bn, 256, 0, stream>>>(pawe, msb, out);
}

// Round 9
// 248.145 us; speedup vs baseline: 1.3434x; 1.2832x over previous
//
#include <hip/hip_runtime.h>
#include <hip/hip_bf16.h>

// Fused additive-attention (Bahdanau-style) on MI355X.
//   att1 = enc @ W_enc + b_enc            [B,L,A]  (bf16 MFMA, fp32 accum)
//   att2 = dh @ W_dec + b_dec             [B,A]
//   s    = tanh(att1+att2) . W_full       [B,L]    (b_full dropped: softmax-invariant)
//   alpha= softmax_L(s); awe = sum_l alpha * att1  [B,A]
// Flash-style two-level softmax: att1 never hits HBM.
//
// R9 vs R6 (246.8us best; R7/R8 structural regressions reverted):
//   Geometry = R6 exactly (TM=64, 16 waves x (64r x 32c), acc[4][2]=32 AGPR,
//   B-reg double-set). NEW: raw-barrier pipeline --
//   - __syncthreads() -> {s_waitcnt lgkmcnt(0); s_barrier} inline asm with
//     memory clobber: LDS handoff stays safe, but global loads (B prefetch,
//     enc prefetch) are NOT drained at barriers (the vmcnt(0) drain was
//     serializing all 4 resource floors, ~220us = their SUM).
//   - compiler-counted vmcnt before each use (no hand vmcnt -> no ledger bugs)
//   - enc prefetch 4 phases deep (4 float4 slots, ~1250cyc > 900cyc HBM lat)
//   - one barrier per 64-K phase, double-buffered A-LDS
//   - s_setprio(1) around MFMA cluster (T5; phases now have role diversity)

#define Bn 64
#define Ln 1024
#define En 2048
#define An 512
#define TM 64          // l-rows per workgroup
#define NTILES (Ln/TM) // 16
#define AWE_OFF 0
#define ALPHA_OFF (Bn*An) // 32768
#define TILEB 8192     // bytes per A k-tile LDS buffer (64 rows x 128B)

using short8 = __attribute__((ext_vector_type(8))) short;
using sh4    = __attribute__((ext_vector_type(4))) short;
using f32x4  = __attribute__((ext_vector_type(4))) float;

__device__ inline short f2bf(float x){
    unsigned u = __builtin_bit_cast(unsigned, x);
    unsigned r = (u + 0x7fffu + ((u >> 16) & 1u)) >> 16;
    return (short)r;
}
__device__ inline float tanh_fast(float x){
    return 2.0f * __frcp_rn(1.0f + __expf(-2.0f * x)) - 1.0f;
}

// ---------- kernel 0: W_enc fragment-pack  +  att2 GEMV (merged) ----------
__global__ __launch_bounds__(256) void k_prep(const float* __restrict__ W,
                                              unsigned short* __restrict__ Wp,
                                              const float* __restrict__ dh,
                                              const float* __restrict__ Wd,
                                              const float* __restrict__ bd,
                                              float* __restrict__ att2){
    __shared__ float dl[512];
    int blk = blockIdx.x, tid = threadIdx.x;
    if (blk < 512){
        int t = blk * 256 + tid;
        int f = t >> 6, lane = t & 63;
        int kb = f >> 5, nc = f & 31;
        int k0 = kb * 32 + (lane >> 4) * 8;
        int col = nc * 16 + (lane & 15);
        short8 v;
#pragma unroll
        for (int j = 0; j < 8; ++j)
            v[j] = f2bf(W[(size_t)(k0 + j) * An + col]);
        *(short8*)(Wp + (size_t)f * 512 + lane * 8) = v;
    } else {
        int b = blk - 512;
        dl[tid]       = dh[b * 512 + tid];
        dl[tid + 256] = dh[b * 512 + tid + 256];
        __syncthreads();
        for (int a = tid; a < An; a += 256){
            float s = bd[a];
            for (int k = 0; k < 512; ++k)
                s = fmaf(dl[k], Wd[(size_t)k * An + a], s);
            att2[b * An + a] = s;
        }
    }
}

// ---------- kernel 1: fused GEMM + score + tile-softmax + partial awe ----------
// 1024 threads = 16 waves, wave w owns rows 0..63 x cols [w*32, w*32+32).

#define MFMA(a, b, c) __builtin_amdgcn_mfma_f32_16x16x32_bf16((a), (b), (c), 0, 0, 0)

// Issue phase-P B loads (4 frags) into set S. P pre-clamped by caller.
#define BLOAD(S, P)                                                           \
    { const unsigned short* bp = Bbase + (size_t)(P) * 32768;                 \
      S##00 = *(const short8*)(bp);                                           \
      S##01 = *(const short8*)(bp + 512);                                     \
      S##10 = *(const short8*)(bp + 16384);                                   \
      S##11 = *(const short8*)(bp + 16384 + 512); }

#define STAGE(Q, R)                                                           \
    { sh4 sv;                                                                 \
      sv[0] = f2bf(R.x); sv[1] = f2bf(R.y);                                   \
      sv[2] = f2bf(R.z); sv[3] = f2bf(R.w);                                   \
      *(sh4*)(swp + (Q) * TILEB) = sv; }

// 16 MFMAs for buffer Q using landed register set S.
#define MFMAS(Q, S)                                                           \
    _Pragma("unroll")                                                         \
    for (int mi = 0; mi < 4; ++mi){                                           \
        short8 af0 = *(const short8*)(as0 + (Q) * TILEB + mi * 2048);         \
        short8 af1 = *(const short8*)(as1 + (Q) * TILEB + mi * 2048);         \
        acc[mi][0] = MFMA(af0, S##00, acc[mi][0]);                            \
        acc[mi][1] = MFMA(af0, S##01, acc[mi][1]);                            \
        acc[mi][0] = MFMA(af1, S##10, acc[mi][0]);                            \
        acc[mi][1] = MFMA(af1, S##11, acc[mi][1]);                            \
    }

// Raw barrier: drain LDS ops only; global loads stay in flight.
#define PBAR asm volatile("s_waitcnt lgkmcnt(0)\n\ts_barrier" ::: "memory")

// One 64-K phase. Reads Q[P&1] with B set FC (landed); stages tile P+1 into
// Q[(P+1)&1] from SLOT (enc, 4 phases old); refills SLOT with enc(P+5);
// issues B(P+1) into FN.
#define PHASE(P, QC, QN, SLOT, FC, FN)                                        \
{                                                                             \
    BLOAD(FN, ((P) + 1 > 31 ? 31 : (P) + 1))                                  \
    STAGE(QN, SLOT)                                                           \
    SLOT = *(const float4*)(apt + ((P) + 5 > 31 ? 31 : (P) + 5) * 64);        \
    __builtin_amdgcn_s_setprio(1);                                            \
    MFMAS(QC, FC)                                                             \
    __builtin_amdgcn_s_setprio(0);                                            \
    PBAR;                                                                     \
}

__global__ __launch_bounds__(1024)
void k_main(const float* __restrict__ enc, const unsigned short* __restrict__ Wp,
            const float* __restrict__ benc, const float* __restrict__ att2,
            const float* __restrict__ wfull, float* __restrict__ out,
            float* __restrict__ pawe_ws, float* __restrict__ ms_ws){
    const int wg   = blockIdx.x;            // 0..1023
    const int b    = wg >> 4;
    const int tile = wg & 15;
    const int l0   = tile * TM;
    const int tid  = threadIdx.x;
    const int lane = tid & 63, w = tid >> 6;   // w = 0..15 (col-group)

    __shared__ alignas(16) unsigned short Alds[2][TM * 64];  // 2 x 8 KB, XOR-swizzled
    __shared__ float red[16][TM];              // per-wave row score partials
    __shared__ float plds[TM];                 // tile-local exp(s - m)
    char* const alds = (char*)Alds;

    f32x4 acc[4][2];
#pragma unroll
    for (int mi = 0; mi < 4; ++mi)
#pragma unroll
        for (int ni = 0; ni < 2; ++ni)
            acc[mi][ni] = (f32x4){0.f, 0.f, 0.f, 0.f};

    // staging: thread loads 4 fp32 (16B) of row (tid>>4), k-chunk (tid&15)*4
    const int srow  = tid >> 4;
    const int sbyte = srow * 128 + (((tid & 15) * 8) ^ ((srow & 7) << 4));
    char* const swp = alds + sbyte;
    const float* apt = enc + ((size_t)(b * Ln + l0 + srow)) * En + (tid & 15) * 4;

    // B fragments: f = (p*2+s)*32 + w*2 + ni ; addr = Wp + f*512 + lane*8
    const unsigned short* Bbase = Wp + (size_t)(w * 2) * 512 + lane * 8;

    // A fragments: row = mi*16 + (lane&15); k-byte = (s*64 + akb) ^ sw (full XOR)
    const int arow = lane & 15;
    const int akb  = (lane >> 4) * 16;
    const int sw   = (arow & 7) << 4;
    const char* const as0 = alds + arow * 128 + (akb ^ sw);
    const char* const as1 = alds + arow * 128 + ((64 + akb) ^ sw);

    // B register sets (double-buffered across phases)
    short8 fa00, fa01, fa10, fa11;   // even phases
    short8 fb00, fb01, fb10, fb11;   // odd phases

    // enc prefetch slots: phase P consumes S[(P+1)&3], refills with enc(P+5).
    float4 S0, S1, S2, S3;

    // prologue: tile 0 staged; slots hold enc(1..4); B(0) in fa.
    float4 e0 = *(const float4*)(apt);
    S1 = *(const float4*)(apt + 64);
    S2 = *(const float4*)(apt + 128);
    S3 = *(const float4*)(apt + 192);
    S0 = *(const float4*)(apt + 256);
    BLOAD(fa, 0)
    STAGE(0, e0)
    PBAR;

    for (int sp = 0; sp < 8; ++sp){
        const int p = sp * 4;
        PHASE(p + 0, 0, 1, S1, fa, fb)
        PHASE(p + 1, 1, 0, S2, fb, fa)
        PHASE(p + 2, 0, 1, S3, fa, fb)
        PHASE(p + 3, 1, 0, S0, fb, fa)
    }

    // ---- epilogue ----
    float be[2], a2[2], wfv[2];
    const int cbase = w * 32 + (lane & 15);
#pragma unroll
    for (int ni = 0; ni < 2; ++ni){
        int c = cbase + ni * 16;
        be[ni]  = benc[c];
        a2[ni]  = att2[b * An + c];
        wfv[ni] = wfull[c];
    }

    float tsum[4][4];
#pragma unroll
    for (int mi = 0; mi < 4; ++mi)
#pragma unroll
        for (int j = 0; j < 4; ++j)
            tsum[mi][j] = 0.f;
#pragma unroll
    for (int mi = 0; mi < 4; ++mi)
#pragma unroll
        for (int ni = 0; ni < 2; ++ni)
#pragma unroll
            for (int j = 0; j < 4; ++j){
                float vv = acc[mi][ni][j] + be[ni];
                acc[mi][ni][j] = vv;
                tsum[mi][j] += tanh_fast(vv + a2[ni]) * wfv[ni];
            }

#pragma unroll
    for (int mi = 0; mi < 4; ++mi)
#pragma unroll
        for (int j = 0; j < 4; ++j){
            float t = tsum[mi][j];
            t += __shfl_xor(t, 1); t += __shfl_xor(t, 2);
            t += __shfl_xor(t, 4); t += __shfl_xor(t, 8);
            if ((lane & 15) == 0)
                red[w][mi * 16 + (lane >> 4) * 4 + j] = t;
        }
    __syncthreads();

    if (tid < 64){   // wave 0: combine 16 wave-partials, tile softmax stats
        float s = 0.f;
#pragma unroll
        for (int k = 0; k < 16; ++k)
            s += red[k][tid];
        out[ALPHA_OFF + b * Ln + l0 + tid] = s;   // raw score; finalized in k_final
        float m = s;
        m = fmaxf(m, __shfl_xor(m, 1));  m = fmaxf(m, __shfl_xor(m, 2));
        m = fmaxf(m, __shfl_xor(m, 4));  m = fmaxf(m, __shfl_xor(m, 8));
        m = fmaxf(m, __shfl_xor(m, 16)); m = fmaxf(m, __shfl_xor(m, 32));
        float pv = __expf(s - m);
        float sm = pv;
        sm += __shfl_xor(sm, 1);  sm += __shfl_xor(sm, 2);
        sm += __shfl_xor(sm, 4);  sm += __shfl_xor(sm, 8);
        sm += __shfl_xor(sm, 16); sm += __shfl_xor(sm, 32);
        plds[tid] = pv;
        if (tid == 0){ ms_ws[wg * 2] = m; ms_ws[wg * 2 + 1] = sm; }
    }
    __syncthreads();

    // partial awe for this wave's 32 cols (rows complete within the wave)
    float pp0 = 0.f, pp1 = 0.f;
#pragma unroll
    for (int mi = 0; mi < 4; ++mi)
#pragma unroll
        for (int j = 0; j < 4; ++j){
            float pr = plds[mi * 16 + (lane >> 4) * 4 + j];
            pp0 += pr * acc[mi][0][j];
            pp1 += pr * acc[mi][1][j];
        }
    pp0 += __shfl_xor(pp0, 16); pp0 += __shfl_xor(pp0, 32);
    pp1 += __shfl_xor(pp1, 16); pp1 += __shfl_xor(pp1, 32);
    if (lane < 16){
        pawe_ws[(size_t)wg * An + w * 32 + lane]      = pp0;
        pawe_ws[(size_t)wg * An + w * 32 + 16 + lane] = pp1;
    }
}

// ---------- kernel 2: combine tiles, finalize awe + alpha ----------
__global__ __launch_bounds__(256) void k_final(const float* __restrict__ pawe,
                                               const float* __restrict__ ms,
                                               float* __restrict__ out){
    int b = blockIdx.x, tid = threadIdx.x;
    __shared__ float scale[NTILES];
    __shared__ float sh[2];   // inv_total, global max
    if (tid < 64){
        int lane = tid;
        float m = -1e30f, su = 0.f;
        if (lane < NTILES){ m = ms[(b * NTILES + lane) * 2]; su = ms[(b * NTILES + lane) * 2 + 1]; }
        float mm = m;
        mm = fmaxf(mm, __shfl_xor(mm, 1)); mm = fmaxf(mm, __shfl_xor(mm, 2));
        mm = fmaxf(mm, __shfl_xor(mm, 4)); mm = fmaxf(mm, __shfl_xor(mm, 8));
        float sc = (lane < NTILES) ? su * __expf(m - mm) : 0.f;
        float tot = sc;
        tot += __shfl_xor(tot, 1); tot += __shfl_xor(tot, 2);
        tot += __shfl_xor(tot, 4); tot += __shfl_xor(tot, 8);
        if (lane < NTILES) scale[lane] = __expf(m - mm);
        if (lane == 0){ sh[0] = 1.0f / tot; sh[1] = mm; }
    }
    __syncthreads();
    float inv = sh[0], mm = sh[1];
    for (int a = tid; a < An; a += 256){
        float s = 0.f;
#pragma unroll
        for (int t = 0; t < NTILES; ++t)
            s += pawe[((size_t)(b * NTILES + t)) * An + a] * scale[t];
        out[AWE_OFF + b * An + a] = s * inv;
    }
    for (int l = tid; l < Ln; l += 256){
        float s = out[ALPHA_OFF + b * Ln + l];
        out[ALPHA_OFF + b * Ln + l] = __expf(s - mm) * inv;
    }
}

extern "C" void kernel_launch(void* const* d_in, const int* in_sizes, int n_in,
                              void* d_out, int out_size, void* d_ws, size_t ws_size,
                              hipStream_t stream){
    const float* enc   = (const float*)d_in[0];
    const float* dh    = (const float*)d_in[1];
    const float* Wenc  = (const float*)d_in[2];
    const float* benc  = (const float*)d_in[3];
    const float* Wdec  = (const float*)d_in[4];
    const float* bdec  = (const float*)d_in[5];
    const float* wfull = (const float*)d_in[6];
    // d_in[7] = b_full: softmax-invariant, unused.
    float* out = (float*)d_out;

    char* ws = (char*)d_ws;
    unsigned short* Wp = (unsigned short*)ws;                       // 2 MB packed W
    float* att2 = (float*)(ws + (2u << 20));                        // 128 KB
    float* pawe = (float*)(ws + (2u << 20) + (128u << 10));         // 2 MB
    float* msb  = (float*)(ws + (4u << 20) + (128u << 10));         // 8 KB

    k_prep<<<576, 256, 0, stream>>>(Wenc, Wp, dh, Wdec, bdec, att2);
    k_main<<<Bn * NTILES, 1024, 0, stream>>>(enc, Wp, benc, att2, wfull, out, pawe, msb);
    k_final<<<Bn, 256, 0, stream>>>(pawe, msb, out);
}

// Round 10
// 247.542 us; speedup vs baseline: 1.3466x; 1.0024x over previous
//
#include <hip/hip_runtime.h>
#include <hip/hip_bf16.h>

// Fused additive-attention (Bahdanau-style) on MI355X.
//   att1 = enc @ W_enc + b_enc            [B,L,A]  (bf16 MFMA, fp32 accum)
//   att2 = dh @ W_dec + b_dec             [B,A]
//   s    = tanh(att1+att2) . W_full       [B,L]    (b_full dropped: softmax-invariant)
//   alpha= softmax_L(s); awe = sum_l alpha * att1  [B,A]
// Flash-style two-level softmax: att1 never hits HBM.
//
// R9 vs R6 (246.8us best; R7/R8 structural regressions reverted):
//   Geometry = R6 exactly (TM=64, 16 waves x (64r x 32c), acc[4][2]=32 AGPR,
//   B-reg double-set). NEW: raw-barrier pipeline --
//   - __syncthreads() -> {s_waitcnt lgkmcnt(0); s_barrier} inline asm with
//     memory clobber: LDS handoff stays safe, but global loads (B prefetch,
//     enc prefetch) are NOT drained at barriers (the vmcnt(0) drain was
//     serializing all 4 resource floors, ~220us = their SUM).
//   - compiler-counted vmcnt before each use (no hand vmcnt -> no ledger bugs)
//   - enc prefetch 4 phases deep (4 float4 slots, ~1250cyc > 900cyc HBM lat)
//   - one barrier per 64-K phase, double-buffered A-LDS
//   - s_setprio(1) around MFMA cluster (T5; phases now have role diversity)

#define Bn 64
#define Ln 1024
#define En 2048
#define An 512
#define TM 64          // l-rows per workgroup
#define NTILES (Ln/TM) // 16
#define AWE_OFF 0
#define ALPHA_OFF (Bn*An) // 32768
#define TILEB 8192     // bytes per A k-tile LDS buffer (64 rows x 128B)

using short8 = __attribute__((ext_vector_type(8))) short;
using sh4    = __attribute__((ext_vector_type(4))) short;
using f32x4  = __attribute__((ext_vector_type(4))) float;

__device__ inline short f2bf(float x){
    unsigned u = __builtin_bit_cast(unsigned, x);
    unsigned r = (u + 0x7fffu + ((u >> 16) & 1u)) >> 16;
    return (short)r;
}
__device__ inline float tanh_fast(float x){
    return 2.0f * __frcp_rn(1.0f + __expf(-2.0f * x)) - 1.0f;
}

// ---------- kernel 0: W_enc fragment-pack  +  att2 GEMV (merged) ----------
__global__ __launch_bounds__(256) void k_prep(const float* __restrict__ W,
                                              unsigned short* __restrict__ Wp,
                                              const float* __restrict__ dh,
                                              const float* __restrict__ Wd,
                                              const float* __restrict__ bd,
                                              float* __restrict__ att2){
    __shared__ float dl[512];
    int blk = blockIdx.x, tid = threadIdx.x;
    if (blk < 512){
        int t = blk * 256 + tid;
        int f = t >> 6, lane = t & 63;
        int kb = f >> 5, nc = f & 31;
        int k0 = kb * 32 + (lane >> 4) * 8;
        int col = nc * 16 + (lane & 15);
        short8 v;
#pragma unroll
        for (int j = 0; j < 8; ++j)
            v[j] = f2bf(W[(size_t)(k0 + j) * An + col]);
        *(short8*)(Wp + (size_t)f * 512 + lane * 8) = v;
    } else {
        int b = blk - 512;
        dl[tid]       = dh[b * 512 + tid];
        dl[tid + 256] = dh[b * 512 + tid + 256];
        __syncthreads();
        for (int a = tid; a < An; a += 256){
            float s = bd[a];
            for (int k = 0; k < 512; ++k)
                s = fmaf(dl[k], Wd[(size_t)k * An + a], s);
            att2[b * An + a] = s;
        }
    }
}

// ---------- kernel 1: fused GEMM + score + tile-softmax + partial awe ----------
// 1024 threads = 16 waves, wave w owns rows 0..63 x cols [w*32, w*32+32).

#define MFMA(a, b, c) __builtin_amdgcn_mfma_f32_16x16x32_bf16((a), (b), (c), 0, 0, 0)

// Issue phase-P B loads (4 frags) into set S. P pre-clamped by caller.
#define BLOAD(S, P)                                                           \
    { const unsigned short* bp = Bbase + (size_t)(P) * 32768;                 \
      S##00 = *(const short8*)(bp);                                           \
      S##01 = *(const short8*)(bp + 512);                                     \
      S##10 = *(const short8*)(bp + 16384);                                   \
      S##11 = *(const short8*)(bp + 16384 + 512); }

#define STAGE(Q, R)                                                           \
    { sh4 sv;                                                                 \
      sv[0] = f2bf(R.x); sv[1] = f2bf(R.y);                                   \
      sv[2] = f2bf(R.z); sv[3] = f2bf(R.w);                                   \
      *(sh4*)(swp + (Q) * TILEB) = sv; }

// 16 MFMAs for buffer Q using landed register set S.
#define MFMAS(Q, S)                                                           \
    _Pragma("unroll")                                                         \
    for (int mi = 0; mi < 4; ++mi){                                           \
        short8 af0 = *(const short8*)(as0 + (Q) * TILEB + mi * 2048);         \
        short8 af1 = *(const short8*)(as1 + (Q) * TILEB + mi * 2048);         \
        acc[mi][0] = MFMA(af0, S##00, acc[mi][0]);                            \
        acc[mi][1] = MFMA(af0, S##01, acc[mi][1]);                            \
        acc[mi][0] = MFMA(af1, S##10, acc[mi][0]);                            \
        acc[mi][1] = MFMA(af1, S##11, acc[mi][1]);                            \
    }

// Raw barrier: drain LDS ops only; global loads stay in flight.
#define PBAR asm volatile("s_waitcnt lgkmcnt(0)\n\ts_barrier" ::: "memory")

// One 64-K phase. Reads Q[P&1] with B set FC (landed); stages tile P+1 into
// Q[(P+1)&1] from SLOT (enc, 4 phases old); refills SLOT with enc(P+5);
// issues B(P+1) into FN.
#define PHASE(P, QC, QN, SLOT, FC, FN)                                        \
{                                                                             \
    BLOAD(FN, ((P) + 1 > 31 ? 31 : (P) + 1))                                  \
    STAGE(QN, SLOT)                                                           \
    SLOT = *(const float4*)(apt + ((P) + 5 > 31 ? 31 : (P) + 5) * 64);        \
    __builtin_amdgcn_s_setprio(1);                                            \
    MFMAS(QC, FC)                                                             \
    __builtin_amdgcn_s_setprio(0);                                            \
    PBAR;                                                                     \
}

__global__ __launch_bounds__(1024)
void k_main(const float* __restrict__ enc, const unsigned short* __restrict__ Wp,
            const float* __restrict__ benc, const float* __restrict__ att2,
            const float* __restrict__ wfull, float* __restrict__ out,
            float* __restrict__ pawe_ws, float* __restrict__ ms_ws){
    const int wg   = blockIdx.x;            // 0..1023
    const int b    = wg >> 4;
    const int tile = wg & 15;
    const int l0   = tile * TM;
    const int tid  = threadIdx.x;
    const int lane = tid & 63, w = tid >> 6;   // w = 0..15 (col-group)

    __shared__ alignas(16) unsigned short Alds[2][TM * 64];  // 2 x 8 KB, XOR-swizzled
    __shared__ float red[16][TM];              // per-wave row score partials
    __shared__ float plds[TM];                 // tile-local exp(s - m)
    char* const alds = (char*)Alds;

    f32x4 acc[4][2];
#pragma unroll
    for (int mi = 0; mi < 4; ++mi)
#pragma unroll
        for (int ni = 0; ni < 2; ++ni)
            acc[mi][ni] = (f32x4){0.f, 0.f, 0.f, 0.f};

    // staging: thread loads 4 fp32 (16B) of row (tid>>4), k-chunk (tid&15)*4
    const int srow  = tid >> 4;
    const int sbyte = srow * 128 + (((tid & 15) * 8) ^ ((srow & 7) << 4));
    char* const swp = alds + sbyte;
    const float* apt = enc + ((size_t)(b * Ln + l0 + srow)) * En + (tid & 15) * 4;

    // B fragments: f = (p*2+s)*32 + w*2 + ni ; addr = Wp + f*512 + lane*8
    const unsigned short* Bbase = Wp + (size_t)(w * 2) * 512 + lane * 8;

    // A fragments: row = mi*16 + (lane&15); k-byte = (s*64 + akb) ^ sw (full XOR)
    const int arow = lane & 15;
    const int akb  = (lane >> 4) * 16;
    const int sw   = (arow & 7) << 4;
    const char* const as0 = alds + arow * 128 + (akb ^ sw);
    const char* const as1 = alds + arow * 128 + ((64 + akb) ^ sw);

    // B register sets (double-buffered across phases)
    short8 fa00, fa01, fa10, fa11;   // even phases
    short8 fb00, fb01, fb10, fb11;   // odd phases

    // enc prefetch slots: phase P consumes S[(P+1)&3], refills with enc(P+5).
    float4 S0, S1, S2, S3;

    // prologue: tile 0 staged; slots hold enc(1..4); B(0) in fa.
    float4 e0 = *(const float4*)(apt);
    S1 = *(const float4*)(apt + 64);
    S2 = *(const float4*)(apt + 128);
    S3 = *(const float4*)(apt + 192);
    S0 = *(const float4*)(apt + 256);
    BLOAD(fa, 0)
    STAGE(0, e0)
    PBAR;

    for (int sp = 0; sp < 8; ++sp){
        const int p = sp * 4;
        PHASE(p + 0, 0, 1, S1, fa, fb)
        PHASE(p + 1, 1, 0, S2, fb, fa)
        PHASE(p + 2, 0, 1, S3, fa, fb)
        PHASE(p + 3, 1, 0, S0, fb, fa)
    }

    // ---- epilogue ----
    float be[2], a2[2], wfv[2];
    const int cbase = w * 32 + (lane & 15);
#pragma unroll
    for (int ni = 0; ni < 2; ++ni){
        int c = cbase + ni * 16;
        be[ni]  = benc[c];
        a2[ni]  = att2[b * An + c];
        wfv[ni] = wfull[c];
    }

    float tsum[4][4];
#pragma unroll
    for (int mi = 0; mi < 4; ++mi)
#pragma unroll
        for (int j = 0; j < 4; ++j)
            tsum[mi][j] = 0.f;
#pragma unroll
    for (int mi = 0; mi < 4; ++mi)
#pragma unroll
        for (int ni = 0; ni < 2; ++ni)
#pragma unroll
            for (int j = 0; j < 4; ++j){
                float vv = acc[mi][ni][j] + be[ni];
                acc[mi][ni][j] = vv;
                tsum[mi][j] += tanh_fast(vv + a2[ni]) * wfv[ni];
            }

#pragma unroll
    for (int mi = 0; mi < 4; ++mi)
#pragma unroll
        for (int j = 0; j < 4; ++j){
            float t = tsum[mi][j];
            t += __shfl_xor(t, 1); t += __shfl_xor(t, 2);
            t += __shfl_xor(t, 4); t += __shfl_xor(t, 8);
            if ((lane & 15) == 0)
                red[w][mi * 16 + (lane >> 4) * 4 + j] = t;
        }
    __syncthreads();

    if (tid < 64){   // wave 0: combine 16 wave-partials, tile softmax stats
        float s = 0.f;
#pragma unroll
        for (int k = 0; k < 16; ++k)
            s += red[k][tid];
        out[ALPHA_OFF + b * Ln + l0 + tid] = s;   // raw score; finalized in k_final
        float m = s;
        m = fmaxf(m, __shfl_xor(m, 1));  m = fmaxf(m, __shfl_xor(m, 2));
        m = fmaxf(m, __shfl_xor(m, 4));  m = fmaxf(m, __shfl_xor(m, 8));
        m = fmaxf(m, __shfl_xor(m, 16)); m = fmaxf(m, __shfl_xor(m, 32));
        float pv = __expf(s - m);
        float sm = pv;
        sm += __shfl_xor(sm, 1);  sm += __shfl_xor(sm, 2);
        sm += __shfl_xor(sm, 4);  sm += __shfl_xor(sm, 8);
        sm += __shfl_xor(sm, 16); sm += __shfl_xor(sm, 32);
        plds[tid] = pv;
        if (tid == 0){ ms_ws[wg * 2] = m; ms_ws[wg * 2 + 1] = sm; }
    }
    __syncthreads();

    // partial awe for this wave's 32 cols (rows complete within the wave)
    float pp0 = 0.f, pp1 = 0.f;
#pragma unroll
    for (int mi = 0; mi < 4; ++mi)
#pragma unroll
        for (int j = 0; j < 4; ++j){
            float pr = plds[mi * 16 + (lane >> 4) * 4 + j];
            pp0 += pr * acc[mi][0][j];
            pp1 += pr * acc[mi][1][j];
        }
    pp0 += __shfl_xor(pp0, 16); pp0 += __shfl_xor(pp0, 32);
    pp1 += __shfl_xor(pp1, 16); pp1 += __shfl_xor(pp1, 32);
    if (lane < 16){
        pawe_ws[(size_t)wg * An + w * 32 + lane]      = pp0;
        pawe_ws[(size_t)wg * An + w * 32 + 16 + lane] = pp1;
    }
}

// ---------- kernel 2: combine tiles, finalize awe + alpha ----------
__global__ __launch_bounds__(256) void k_final(const float* __restrict__ pawe,
                                               const float* __restrict__ ms,
                                               float* __restrict__ out){
    int b = blockIdx.x, tid = threadIdx.x;
    __shared__ float scale[NTILES];
    __shared__ float sh[2];   // inv_total, global max
    if (tid < 64){
        int lane = tid;
        float m = -1e30f, su = 0.f;
        if (lane < NTILES){ m = ms[(b * NTILES + lane) * 2]; su = ms[(b * NTILES + lane) * 2 + 1]; }
        float mm = m;
        mm = fmaxf(mm, __shfl_xor(mm, 1)); mm = fmaxf(mm, __shfl_xor(mm, 2));
        mm = fmaxf(mm, __shfl_xor(mm, 4)); mm = fmaxf(mm, __shfl_xor(mm, 8));
        float sc = (lane < NTILES) ? su * __expf(m - mm) : 0.f;
        float tot = sc;
        tot += __shfl_xor(tot, 1); tot += __shfl_xor(tot, 2);
        tot += __shfl_xor(tot, 4); tot += __shfl_xor(tot, 8);
        if (lane < NTILES) scale[lane] = __expf(m - mm);
        if (lane == 0){ sh[0] = 1.0f / tot; sh[1] = mm; }
    }
    __syncthreads();
    float inv = sh[0], mm = sh[1];
    for (int a = tid; a < An; a += 256){
        float s = 0.f;
#pragma unroll
        for (int t = 0; t < NTILES; ++t)
            s += pawe[((size_t)(b * NTILES + t)) * An + a] * scale[t];
        out[AWE_OFF + b * An + a] = s * inv;
    }
    for (int l = tid; l < Ln; l += 256){
        float s = out[ALPHA_OFF + b * Ln + l];
        out[ALPHA_OFF + b * Ln + l] = __expf(s - mm) * inv;
    }
}

extern "C" void kernel_launch(void* const* d_in, const int* in_sizes, int n_in,
                              void* d_out, int out_size, void* d_ws, size_t ws_size,
                              hipStream_t stream){
    const float* enc   = (const float*)d_in[0];
    const float* dh    = (const float*)d_in[1];
    const float* Wenc  = (const float*)d_in[2];
    const float* benc  = (const float*)d_in[3];
    const float* Wdec  = (const float*)d_in[4];
    const float* bdec  = (const float*)d_in[5];
    const float* wfull = (const float*)d_in[6];
    // d_in[7] = b_full: softmax-invariant, unused.
    float* out = (float*)d_out;

    char* ws = (char*)d_ws;
    unsigned short* Wp = (unsigned short*)ws;                       // 2 MB packed W
    float* att2 = (float*)(ws + (2u << 20));                        // 128 KB
    float* pawe = (float*)(ws + (2u << 20) + (128u << 10));         // 2 MB
    float* msb  = (float*)(ws + (4u << 20) + (128u << 10));         // 8 KB

    k_prep<<<576, 256, 0, stream>>>(Wenc, Wp, dh, Wdec, bdec, att2);
    k_main<<<Bn * NTILES, 1024, 0, stream>>>(enc, Wp, benc, att2, wfull, out, pawe, msb);
    k_final<<<Bn, 256, 0, stream>>>(pawe, msb, out);
}

// Round 11
// 244.913 us; speedup vs baseline: 1.3611x; 1.0107x over previous
//
#include <hip/hip_runtime.h>
#include <hip/hip_bf16.h>

// Fused additive-attention (Bahdanau-style) on MI355X.
//   att1 = enc @ W_enc + b_enc            [B,L,A]  (bf16 MFMA, fp32 accum)
//   att2 = dh @ W_dec + b_dec             [B,A]
//   s    = tanh(att1+att2) . W_full       [B,L]    (b_full dropped: softmax-invariant)
//   alpha= softmax_L(s); awe = sum_l alpha * att1  [B,A]
// Flash-style two-level softmax: att1 never hits HBM.
//
// R11 vs R9/R10 (247.5us, neutral vs R6): the ONLY change is the phase
// barrier encoding. R9's PBAR had a "memory" clobber -> LLVM conservatively
// drains vmcnt(0) before the asm -> identical to __syncthreads(), nullifying
// the whole point. New PBAR (m201 pattern, rule #18):
//   sched_barrier(0); asm volatile("s_waitcnt lgkmcnt(0)"); s_barrier;
//   sched_barrier(0)
// -> LDS handoff safe (lgkm drained + compiler fence), global loads stay in
// flight across barriers; compiler emits counted vmcnt before B/SLOT uses.

#define Bn 64
#define Ln 1024
#define En 2048
#define An 512
#define TM 64          // l-rows per workgroup
#define NTILES (Ln/TM) // 16
#define AWE_OFF 0
#define ALPHA_OFF (Bn*An) // 32768
#define TILEB 8192     // bytes per A k-tile LDS buffer (64 rows x 128B)

using short8 = __attribute__((ext_vector_type(8))) short;
using sh4    = __attribute__((ext_vector_type(4))) short;
using f32x4  = __attribute__((ext_vector_type(4))) float;

__device__ inline short f2bf(float x){
    unsigned u = __builtin_bit_cast(unsigned, x);
    unsigned r = (u + 0x7fffu + ((u >> 16) & 1u)) >> 16;
    return (short)r;
}
__device__ inline float tanh_fast(float x){
    return 2.0f * __frcp_rn(1.0f + __expf(-2.0f * x)) - 1.0f;
}

// ---------- kernel 0: W_enc fragment-pack  +  att2 GEMV (merged) ----------
__global__ __launch_bounds__(256) void k_prep(const float* __restrict__ W,
                                              unsigned short* __restrict__ Wp,
                                              const float* __restrict__ dh,
                                              const float* __restrict__ Wd,
                                              const float* __restrict__ bd,
                                              float* __restrict__ att2){
    __shared__ float dl[512];
    int blk = blockIdx.x, tid = threadIdx.x;
    if (blk < 512){
        int t = blk * 256 + tid;
        int f = t >> 6, lane = t & 63;
        int kb = f >> 5, nc = f & 31;
        int k0 = kb * 32 + (lane >> 4) * 8;
        int col = nc * 16 + (lane & 15);
        short8 v;
#pragma unroll
        for (int j = 0; j < 8; ++j)
            v[j] = f2bf(W[(size_t)(k0 + j) * An + col]);
        *(short8*)(Wp + (size_t)f * 512 + lane * 8) = v;
    } else {
        int b = blk - 512;
        dl[tid]       = dh[b * 512 + tid];
        dl[tid + 256] = dh[b * 512 + tid + 256];
        __syncthreads();
        for (int a = tid; a < An; a += 256){
            float s = bd[a];
            for (int k = 0; k < 512; ++k)
                s = fmaf(dl[k], Wd[(size_t)k * An + a], s);
            att2[b * An + a] = s;
        }
    }
}

// ---------- kernel 1: fused GEMM + score + tile-softmax + partial awe ----------
// 1024 threads = 16 waves, wave w owns rows 0..63 x cols [w*32, w*32+32).

#define MFMA(a, b, c) __builtin_amdgcn_mfma_f32_16x16x32_bf16((a), (b), (c), 0, 0, 0)

// Issue phase-P B loads (4 frags) into set S. P pre-clamped by caller.
#define BLOAD(S, P)                                                           \
    { const unsigned short* bp = Bbase + (size_t)(P) * 32768;                 \
      S##00 = *(const short8*)(bp);                                           \
      S##01 = *(const short8*)(bp + 512);                                     \
      S##10 = *(const short8*)(bp + 16384);                                   \
      S##11 = *(const short8*)(bp + 16384 + 512); }

#define STAGE(Q, R)                                                           \
    { sh4 sv;                                                                 \
      sv[0] = f2bf(R.x); sv[1] = f2bf(R.y);                                   \
      sv[2] = f2bf(R.z); sv[3] = f2bf(R.w);                                   \
      *(sh4*)(swp + (Q) * TILEB) = sv; }

// 16 MFMAs for buffer Q using landed register set S.
#define MFMAS(Q, S)                                                           \
    _Pragma("unroll")                                                         \
    for (int mi = 0; mi < 4; ++mi){                                           \
        short8 af0 = *(const short8*)(as0 + (Q) * TILEB + mi * 2048);         \
        short8 af1 = *(const short8*)(as1 + (Q) * TILEB + mi * 2048);         \
        acc[mi][0] = MFMA(af0, S##00, acc[mi][0]);                            \
        acc[mi][1] = MFMA(af0, S##01, acc[mi][1]);                            \
        acc[mi][0] = MFMA(af1, S##10, acc[mi][0]);                            \
        acc[mi][1] = MFMA(af1, S##11, acc[mi][1]);                            \
    }

// Raw barrier, m201 pattern: drain LDS ops only; NO memory clobber so the
// compiler does NOT force vmcnt(0); sched_barrier(0) is the compiler fence
// keeping ds ops on their side of the barrier.
#define PBAR                                                                  \
    __builtin_amdgcn_sched_barrier(0);                                        \
    asm volatile("s_waitcnt lgkmcnt(0)");                                     \
    __builtin_amdgcn_s_barrier();                                             \
    __builtin_amdgcn_sched_barrier(0)

// One 64-K phase. Reads Q[P&1] with B set FC (landed); stages tile P+1 into
// Q[(P+1)&1] from SLOT (enc, 4 phases old); refills SLOT with enc(P+5);
// issues B(P+1) into FN.
#define PHASE(P, QC, QN, SLOT, FC, FN)                                        \
{                                                                             \
    BLOAD(FN, ((P) + 1 > 31 ? 31 : (P) + 1))                                  \
    STAGE(QN, SLOT)                                                           \
    SLOT = *(const float4*)(apt + ((P) + 5 > 31 ? 31 : (P) + 5) * 64);        \
    __builtin_amdgcn_s_setprio(1);                                            \
    MFMAS(QC, FC)                                                             \
    __builtin_amdgcn_s_setprio(0);                                            \
    PBAR;                                                                     \
}

__global__ __launch_bounds__(1024)
void k_main(const float* __restrict__ enc, const unsigned short* __restrict__ Wp,
            const float* __restrict__ benc, const float* __restrict__ att2,
            const float* __restrict__ wfull, float* __restrict__ out,
            float* __restrict__ pawe_ws, float* __restrict__ ms_ws){
    const int wg   = blockIdx.x;            // 0..1023
    const int b    = wg >> 4;
    const int tile = wg & 15;
    const int l0   = tile * TM;
    const int tid  = threadIdx.x;
    const int lane = tid & 63, w = tid >> 6;   // w = 0..15 (col-group)

    __shared__ alignas(16) unsigned short Alds[2][TM * 64];  // 2 x 8 KB, XOR-swizzled
    __shared__ float red[16][TM];              // per-wave row score partials
    __shared__ float plds[TM];                 // tile-local exp(s - m)
    char* const alds = (char*)Alds;

    f32x4 acc[4][2];
#pragma unroll
    for (int mi = 0; mi < 4; ++mi)
#pragma unroll
        for (int ni = 0; ni < 2; ++ni)
            acc[mi][ni] = (f32x4){0.f, 0.f, 0.f, 0.f};

    // staging: thread loads 4 fp32 (16B) of row (tid>>4), k-chunk (tid&15)*4
    const int srow  = tid >> 4;
    const int sbyte = srow * 128 + (((tid & 15) * 8) ^ ((srow & 7) << 4));
    char* const swp = alds + sbyte;
    const float* apt = enc + ((size_t)(b * Ln + l0 + srow)) * En + (tid & 15) * 4;

    // B fragments: f = (p*2+s)*32 + w*2 + ni ; addr = Wp + f*512 + lane*8
    const unsigned short* Bbase = Wp + (size_t)(w * 2) * 512 + lane * 8;

    // A fragments: row = mi*16 + (lane&15); k-byte = (s*64 + akb) ^ sw (full XOR)
    const int arow = lane & 15;
    const int akb  = (lane >> 4) * 16;
    const int sw   = (arow & 7) << 4;
    const char* const as0 = alds + arow * 128 + (akb ^ sw);
    const char* const as1 = alds + arow * 128 + ((64 + akb) ^ sw);

    // B register sets (double-buffered across phases)
    short8 fa00, fa01, fa10, fa11;   // even phases
    short8 fb00, fb01, fb10, fb11;   // odd phases

    // enc prefetch slots: phase P consumes S[(P+1)&3], refills with enc(P+5).
    float4 S0, S1, S2, S3;

    // prologue: tile 0 staged; slots hold enc(1..4); B(0) in fa.
    float4 e0 = *(const float4*)(apt);
    S1 = *(const float4*)(apt + 64);
    S2 = *(const float4*)(apt + 128);
    S3 = *(const float4*)(apt + 192);
    S0 = *(const float4*)(apt + 256);
    BLOAD(fa, 0)
    STAGE(0, e0)
    PBAR;

    for (int sp = 0; sp < 8; ++sp){
        const int p = sp * 4;
        PHASE(p + 0, 0, 1, S1, fa, fb)
        PHASE(p + 1, 1, 0, S2, fb, fa)
        PHASE(p + 2, 0, 1, S3, fa, fb)
        PHASE(p + 3, 1, 0, S0, fb, fa)
    }

    // ---- epilogue ----
    float be[2], a2[2], wfv[2];
    const int cbase = w * 32 + (lane & 15);
#pragma unroll
    for (int ni = 0; ni < 2; ++ni){
        int c = cbase + ni * 16;
        be[ni]  = benc[c];
        a2[ni]  = att2[b * An + c];
        wfv[ni] = wfull[c];
    }

    float tsum[4][4];
#pragma unroll
    for (int mi = 0; mi < 4; ++mi)
#pragma unroll
        for (int j = 0; j < 4; ++j)
            tsum[mi][j] = 0.f;
#pragma unroll
    for (int mi = 0; mi < 4; ++mi)
#pragma unroll
        for (int ni = 0; ni < 2; ++ni)
#pragma unroll
            for (int j = 0; j < 4; ++j){
                float vv = acc[mi][ni][j] + be[ni];
                acc[mi][ni][j] = vv;
                tsum[mi][j] += tanh_fast(vv + a2[ni]) * wfv[ni];
            }

#pragma unroll
    for (int mi = 0; mi < 4; ++mi)
#pragma unroll
        for (int j = 0; j < 4; ++j){
            float t = tsum[mi][j];
            t += __shfl_xor(t, 1); t += __shfl_xor(t, 2);
            t += __shfl_xor(t, 4); t += __shfl_xor(t, 8);
            if ((lane & 15) == 0)
                red[w][mi * 16 + (lane >> 4) * 4 + j] = t;
        }
    __syncthreads();

    if (tid < 64){   // wave 0: combine 16 wave-partials, tile softmax stats
        float s = 0.f;
#pragma unroll
        for (int k = 0; k < 16; ++k)
            s += red[k][tid];
        out[ALPHA_OFF + b * Ln + l0 + tid] = s;   // raw score; finalized in k_final
        float m = s;
        m = fmaxf(m, __shfl_xor(m, 1));  m = fmaxf(m, __shfl_xor(m, 2));
        m = fmaxf(m, __shfl_xor(m, 4));  m = fmaxf(m, __shfl_xor(m, 8));
        m = fmaxf(m, __shfl_xor(m, 16)); m = fmaxf(m, __shfl_xor(m, 32));
        float pv = __expf(s - m);
        float sm = pv;
        sm += __shfl_xor(sm, 1);  sm += __shfl_xor(sm, 2);
        sm += __shfl_xor(sm, 4);  sm += __shfl_xor(sm, 8);
        sm += __shfl_xor(sm, 16); sm += __shfl_xor(sm, 32);
        plds[tid] = pv;
        if (tid == 0){ ms_ws[wg * 2] = m; ms_ws[wg * 2 + 1] = sm; }
    }
    __syncthreads();

    // partial awe for this wave's 32 cols (rows complete within the wave)
    float pp0 = 0.f, pp1 = 0.f;
#pragma unroll
    for (int mi = 0; mi < 4; ++mi)
#pragma unroll
        for (int j = 0; j < 4; ++j){
            float pr = plds[mi * 16 + (lane >> 4) * 4 + j];
            pp0 += pr * acc[mi][0][j];
            pp1 += pr * acc[mi][1][j];
        }
    pp0 += __shfl_xor(pp0, 16); pp0 += __shfl_xor(pp0, 32);
    pp1 += __shfl_xor(pp1, 16); pp1 += __shfl_xor(pp1, 32);
    if (lane < 16){
        pawe_ws[(size_t)wg * An + w * 32 + lane]      = pp0;
        pawe_ws[(size_t)wg * An + w * 32 + 16 + lane] = pp1;
    }
}

// ---------- kernel 2: combine tiles, finalize awe + alpha ----------
__global__ __launch_bounds__(256) void k_final(const float* __restrict__ pawe,
                                               const float* __restrict__ ms,
                                               float* __restrict__ out){
    int b = blockIdx.x, tid = threadIdx.x;
    __shared__ float scale[NTILES];
    __shared__ float sh[2];   // inv_total, global max
    if (tid < 64){
        int lane = tid;
        float m = -1e30f, su = 0.f;
        if (lane < NTILES){ m = ms[(b * NTILES + lane) * 2]; su = ms[(b * NTILES + lane) * 2 + 1]; }
        float mm = m;
        mm = fmaxf(mm, __shfl_xor(mm, 1)); mm = fmaxf(mm, __shfl_xor(mm, 2));
        mm = fmaxf(mm, __shfl_xor(mm, 4)); mm = fmaxf(mm, __shfl_xor(mm, 8));
        float sc = (lane < NTILES) ? su * __expf(m - mm) : 0.f;
        float tot = sc;
        tot += __shfl_xor(tot, 1); tot += __shfl_xor(tot, 2);
        tot += __shfl_xor(tot, 4); tot += __shfl_xor(tot, 8);
        if (lane < NTILES) scale[lane] = __expf(m - mm);
        if (lane == 0){ sh[0] = 1.0f / tot; sh[1] = mm; }
    }
    __syncthreads();
    float inv = sh[0], mm = sh[1];
    for (int a = tid; a < An; a += 256){
        float s = 0.f;
#pragma unroll
        for (int t = 0; t < NTILES; ++t)
            s += pawe[((size_t)(b * NTILES + t)) * An + a] * scale[t];
        out[AWE_OFF + b * An + a] = s * inv;
    }
    for (int l = tid; l < Ln; l += 256){
        float s = out[ALPHA_OFF + b * Ln + l];
        out[ALPHA_OFF + b * Ln + l] = __expf(s - mm) * inv;
    }
}

extern "C" void kernel_launch(void* const* d_in, const int* in_sizes, int n_in,
                              void* d_out, int out_size, void* d_ws, size_t ws_size,
                              hipStream_t stream){
    const float* enc   = (const float*)d_in[0];
    const float* dh    = (const float*)d_in[1];
    const float* Wenc  = (const float*)d_in[2];
    const float* benc  = (const float*)d_in[3];
    const float* Wdec  = (const float*)d_in[4];
    const float* bdec  = (const float*)d_in[5];
    const float* wfull = (const float*)d_in[6];
    // d_in[7] = b_full: softmax-invariant, unused.
    float* out = (float*)d_out;

    char* ws = (char*)d_ws;
    unsigned short* Wp = (unsigned short*)ws;                       // 2 MB packed W
    float* att2 = (float*)(ws + (2u << 20));                        // 128 KB
    float* pawe = (float*)(ws + (2u << 20) + (128u << 10));         // 2 MB
    float* msb  = (float*)(ws + (4u << 20) + (128u << 10));         // 8 KB

    k_prep<<<576, 256, 0, stream>>>(Wenc, Wp, dh, Wdec, bdec, att2);
    k_main<<<Bn * NTILES, 1024, 0, stream>>>(enc, Wp, benc, att2, wfull, out, pawe, msb);
    k_final<<<Bn, 256, 0, stream>>>(pawe, msb, out);
}